// Round 3
// baseline (163.266 us; speedup 1.0000x reference)
//
#include <hip/hip_runtime.h>
#include <cstdint>

#define B_ 2
#define H_ 16
#define S_ 2048
#define DK_ 64
#define BH_ (B_*H_)
#define NQT 32    // 64-row q tiles

typedef __attribute__((ext_vector_type(8))) short short8;
typedef __attribute__((ext_vector_type(4))) short short4v;
typedef __attribute__((ext_vector_type(4))) float floatx4;

__device__ inline unsigned short f2bf(float f) {
  union { float f; unsigned u; } v; v.f = f;
  unsigned u = v.u;
  unsigned r = u + 0x7fffu + ((u >> 16) & 1u);   // RNE
  return (unsigned short)(r >> 16);
}

__device__ inline floatx4 mfma16(short4v a, short4v b, floatx4 c) {
#if __has_builtin(__builtin_amdgcn_mfma_f32_16x16x16bf16_1k)
  return __builtin_amdgcn_mfma_f32_16x16x16bf16_1k(a, b, c, 0, 0, 0);
#else
  asm("v_mfma_f32_16x16x16_bf16 %0, %1, %2, %0" : "+v"(c) : "v"(a), "v"(b));
  return c;
#endif
}

__device__ inline short4v u2s4(unsigned a, unsigned b) {
  union { unsigned u[2]; short4v s; } v;
  v.u[0] = a; v.u[1] = b;
  return v.s;
}

// -------- prologue: K -> bf16 rows; V -> bf16 transposed [bh][d][s] (straight) ------
// (no s-permutation needed anymore: fa_kernel reads V^T fragments as 8B global loads)
__global__ __launch_bounds__(256) void conv_kv(const float* __restrict__ K,
                                               const float* __restrict__ V,
                                               unsigned short* __restrict__ Kb,
                                               unsigned short* __restrict__ Vb) {
  __shared__ __align__(16) unsigned short t[64 * 80];
  const int bh = blockIdx.y, s0 = blockIdx.x * 64;
  const int row = threadIdx.x >> 2, cp = threadIdx.x & 3;

  { // K: straight convert, coalesced
    const float* src = K + ((size_t)(bh * S_ + s0 + row)) * DK_ + cp * 16;
    unsigned short* dst = Kb + ((size_t)(bh * S_ + s0 + row)) * DK_ + cp * 16;
    #pragma unroll
    for (int h = 0; h < 2; ++h) {
      float4 a = *(const float4*)(src + h * 8);
      float4 b = *(const float4*)(src + h * 8 + 4);
      uint4 st;
      st.x = (unsigned)f2bf(a.x) | ((unsigned)f2bf(a.y) << 16);
      st.y = (unsigned)f2bf(a.z) | ((unsigned)f2bf(a.w) << 16);
      st.z = (unsigned)f2bf(b.x) | ((unsigned)f2bf(b.y) << 16);
      st.w = (unsigned)f2bf(b.z) | ((unsigned)f2bf(b.w) << 16);
      *(uint4*)(dst + h * 8) = st;
    }
  }
  { // V: transpose via LDS, straight store
    const float* src = V + ((size_t)(bh * S_ + s0 + row)) * DK_ + cp * 16;
    #pragma unroll
    for (int j4 = 0; j4 < 4; ++j4) {
      float4 a = *(const float4*)(src + j4 * 4);
      int c = cp * 16 + j4 * 4;
      t[(c + 0) * 80 + row] = f2bf(a.x);
      t[(c + 1) * 80 + row] = f2bf(a.y);
      t[(c + 2) * 80 + row] = f2bf(a.z);
      t[(c + 3) * 80 + row] = f2bf(a.w);
    }
    __syncthreads();
    // this thread owns d-row `row`, s-range [s0 + cp*16, +16)
    unsigned short* dst = Vb + ((size_t)(bh * DK_ + row)) * S_ + s0 + cp * 16;
    *(uint4*)(dst + 0) = *(const uint4*)&t[row * 80 + cp * 16];
    *(uint4*)(dst + 8) = *(const uint4*)&t[row * 80 + cp * 16 + 8];
  }
}

// -------- flash attention: s-split, zero-LDS main loop, register double-buffer -----
// Each wave owns a 16-s slice x all 64 q of its block's 64x64 tile:
//   - K A-frags (disjoint 16 rows/wave) and V^T A-frags (disjoint 16 s-cols/wave)
//     load GLOBAL->REG directly (L2-resident): no LDS staging, no barriers, 1x traffic
//     (vs 4x LDS read amplification of the q-split form).
//   - distance-1 register prefetch: next tile's 6 loads issue before this tile's math.
//   - per-wave O^T partial spans 64q x 64d (16 floatx4); 4-way cross-wave reduction
//     through 32 KB LDS once per block at the end (2 rounds of dblk-halves).
__global__ __launch_bounds__(256, 3)
void fa_kernel(const float* __restrict__ Q, const unsigned short* __restrict__ Kb,
               const unsigned short* __restrict__ Vb, float* __restrict__ Out) {
  __shared__ floatx4 OredV[4 * 2 * 4 * 64];   // [wave][db2][nq][lane] = 32 KB
  __shared__ float   Lred[4 * 4 * 16];        // [wave][nq][l16]

  const int tid  = threadIdx.x;
  const int wave = tid >> 6;        // = ws: 16-s slice within the 64-s kv tile
  const int lane = tid & 63;
  const int quad = lane >> 4;
  const int l16  = lane & 15;

  // XCD-aware decode + LPT (heaviest q-tiles first)
  const int id = blockIdx.x;
  const int bh = (id & 7) | (((id >> 3) & 3) << 3);
  const int qt = NQT - 1 - (id >> 5);   // 31..0
  const int nkv = qt + 1;

  const float SCL = 0.125f * 1.44269504088896340736f;  // 1/sqrt(64)*log2(e), folded into Q

  // ---- Q fragments, B-operand of S^T=K*Q^T: [nq*2+ks], lane n=q=l16, k=d=quad*8+j
  short8 qf[8];
  #pragma unroll
  for (int nq = 0; nq < 4; ++nq) {
    const float* p = Q + ((size_t)bh * S_ + qt * 64 + nq * 16 + l16) * DK_ + quad * 8;
    #pragma unroll
    for (int ks = 0; ks < 2; ++ks) {
      float4 x = *(const float4*)(p + ks * 32);
      float4 y = *(const float4*)(p + ks * 32 + 4);
      short8 t;
      t[0]=(short)f2bf(x.x*SCL); t[1]=(short)f2bf(x.y*SCL); t[2]=(short)f2bf(x.z*SCL); t[3]=(short)f2bf(x.w*SCL);
      t[4]=(short)f2bf(y.x*SCL); t[5]=(short)f2bf(y.y*SCL); t[6]=(short)f2bf(y.z*SCL); t[7]=(short)f2bf(y.w*SCL);
      qf[nq * 2 + ks] = t;
    }
  }

  floatx4 Ot[4][4];                 // O^T partials [dblk][nq] over this wave's s-slices
  float ls[4] = {0.f, 0.f, 0.f, 0.f};
  #pragma unroll
  for (int d = 0; d < 4; ++d)
    #pragma unroll
    for (int nq = 0; nq < 4; ++nq) Ot[d][nq] = (floatx4){0,0,0,0};

  // K A-frag (16x16x32): lane reads K[kv*64 + wave*16 + l16][quad*8 + ks*32 .. +8]
  const unsigned short* pK = Kb + (((size_t)bh * S_ + wave * 16 + l16) << 6) + quad * 8;
  // V^T A-frag (16x16x16): lane reads Vt[dblk*16 + l16][kv*64 + wave*16 + quad*4 .. +4]
  const unsigned short* pV = Vb + (((size_t)bh * DK_ + l16) << 11) + wave * 16 + quad * 4;

  short8  ck0 = *(const short8*)pK;
  short8  ck1 = *(const short8*)(pK + 32);
  short4v cv0 = *(const short4v*)(pV);
  short4v cv1 = *(const short4v*)(pV + 16 * 2048);
  short4v cv2 = *(const short4v*)(pV + 32 * 2048);
  short4v cv3 = *(const short4v*)(pV + 48 * 2048);

  for (int kv = 0; kv < nkv; ++kv) {
    const bool last = (kv == nkv - 1);
    short8 nk0, nk1; short4v nv0, nv1, nv2, nv3;
    if (!last) {        // issue next tile's 6 loads before this tile's math
      pK += 4096; pV += 64;
      nk0 = *(const short8*)pK;
      nk1 = *(const short8*)(pK + 32);
      nv0 = *(const short4v*)(pV);
      nv1 = *(const short4v*)(pV + 16 * 2048);
      nv2 = *(const short4v*)(pV + 32 * 2048);
      nv3 = *(const short4v*)(pV + 48 * 2048);
    }
    // ---- QK^T + softmax-exp for the wave's 16-s x 64-q strip
    unsigned pk[4][2];
    #pragma unroll
    for (int nq = 0; nq < 4; ++nq) {
      if (last && nq < wave) continue;      // strip fully above diagonal (wave-uniform)
      floatx4 s0 = (floatx4){0,0,0,0};
      __builtin_amdgcn_s_setprio(1);
      s0 = __builtin_amdgcn_mfma_f32_16x16x32_bf16(ck0, qf[nq * 2 + 0], s0, 0, 0, 0);
      s0 = __builtin_amdgcn_mfma_f32_16x16x32_bf16(ck1, qf[nq * 2 + 1], s0, 0, 0, 0);
      __builtin_amdgcn_s_setprio(0);
      if (last && nq == wave) {   // diagonal 16x16: lane holds q=l16, s=quad*4+r
        #pragma unroll
        for (int r = 0; r < 4; ++r)
          if (quad * 4 + r > l16) s0[r] = -INFINITY;
      }
      float e0 = __builtin_amdgcn_exp2f(s0[0]);
      float e1 = __builtin_amdgcn_exp2f(s0[1]);
      float e2 = __builtin_amdgcn_exp2f(s0[2]);
      float e3 = __builtin_amdgcn_exp2f(s0[3]);
      ls[nq] += (e0 + e1) + (e2 + e3);
      pk[nq][0] = __builtin_amdgcn_perm(__float_as_uint(e1) + 0x8000u,
                                        __float_as_uint(e0) + 0x8000u, 0x07060302u);
      pk[nq][1] = __builtin_amdgcn_perm(__float_as_uint(e3) + 0x8000u,
                                        __float_as_uint(e2) + 0x8000u, 0x07060302u);
    }
    // ---- O^T += V^T * P^T : 16 independent accumulator chains
    __builtin_amdgcn_s_setprio(1);
    #pragma unroll
    for (int nq = 0; nq < 4; ++nq) {
      if (last && nq < wave) continue;
      const short4v pb = u2s4(pk[nq][0], pk[nq][1]);
      Ot[0][nq] = mfma16(cv0, pb, Ot[0][nq]);
      Ot[1][nq] = mfma16(cv1, pb, Ot[1][nq]);
      Ot[2][nq] = mfma16(cv2, pb, Ot[2][nq]);
      Ot[3][nq] = mfma16(cv3, pb, Ot[3][nq]);
    }
    __builtin_amdgcn_s_setprio(0);
    if (!last) { ck0 = nk0; ck1 = nk1; cv0 = nv0; cv1 = nv1; cv2 = nv2; cv3 = nv3; }
  }

  // ---- epilogue: 4-way cross-wave reduction (2 rounds of dblk-halves, 32 KB LDS)
  #pragma unroll
  for (int nq = 0; nq < 4; ++nq) {
    ls[nq] += __shfl_xor(ls[nq], 16);
    ls[nq] += __shfl_xor(ls[nq], 32);
  }
  if (lane < 16) {
    #pragma unroll
    for (int nq = 0; nq < 4; ++nq) Lred[(wave * 4 + nq) * 16 + lane] = ls[nq];
  }
  float inv = 0.f;
  #pragma unroll
  for (int rnd = 0; rnd < 2; ++rnd) {
    #pragma unroll
    for (int db = 0; db < 2; ++db)
      #pragma unroll
      for (int nq = 0; nq < 4; ++nq)
        OredV[((wave * 2 + db) * 4 + nq) * 64 + lane] = Ot[rnd * 2 + db][nq];
    __syncthreads();
    if (rnd == 0) {
      const float lt = Lred[(0 * 4 + wave) * 16 + l16] + Lred[(1 * 4 + wave) * 16 + l16]
                     + Lred[(2 * 4 + wave) * 16 + l16] + Lred[(3 * 4 + wave) * 16 + l16];
      inv = 1.0f / lt;
    }
    // wave w owns output q-rows [qt*64 + w*16, +16): sum its nq=w tiles over waves
    #pragma unroll
    for (int db = 0; db < 2; ++db) {
      floatx4 s = OredV[((0 * 2 + db) * 4 + wave) * 64 + lane]
                + OredV[((1 * 2 + db) * 4 + wave) * 64 + lane]
                + OredV[((2 * 2 + db) * 4 + wave) * 64 + lane]
                + OredV[((3 * 2 + db) * 4 + wave) * 64 + lane];
      s *= inv;
      // lane holds q = wave*16 + l16 (col), d = (rnd*2+db)*16 + quad*4 + r (row)
      *(floatx4*)(Out + ((size_t)(bh * S_ + qt * 64 + wave * 16 + l16)) * 64
                      + (rnd * 2 + db) * 16 + quad * 4) = s;
    }
    if (rnd == 0) __syncthreads();   // WAR before round-1 overwrites OredV
  }
}

extern "C" void kernel_launch(void* const* d_in, const int* in_sizes, int n_in,
                              void* d_out, int out_size, void* d_ws, size_t ws_size,
                              hipStream_t stream) {
  const float* Q = (const float*)d_in[0];
  const float* K = (const float*)d_in[1];
  const float* V = (const float*)d_in[2];
  // d_in[3] = d_k (=64), d_in[4] = causal tril mask (applied analytically)
  float* Out = (float*)d_out;
  unsigned short* Kb = (unsigned short*)d_ws;                    // 8.4 MB
  unsigned short* Vb = Kb + (size_t)BH_ * S_ * DK_;              // 8.4 MB
  conv_kv<<<dim3(S_ / 64, BH_), 256, 0, stream>>>(K, V, Kb, Vb);
  fa_kernel<<<dim3(NQT * BH_), 256, 0, stream>>>(Q, Kb, Vb, Out);
}

// Round 4
// 144.469 us; speedup vs baseline: 1.1301x; 1.1301x over previous
//
#include <hip/hip_runtime.h>
#include <cstdint>

#define B_ 2
#define H_ 16
#define S_ 2048
#define DK_ 64
#define BH_ (B_*H_)
#define NQT 32    // 64-row q tiles

typedef __attribute__((ext_vector_type(8))) short short8;
typedef __attribute__((ext_vector_type(4))) short short4v;
typedef __attribute__((ext_vector_type(4))) float floatx4;

__device__ inline unsigned short f2bf(float f) {
  union { float f; unsigned u; } v; v.f = f;
  unsigned u = v.u;
  unsigned r = u + 0x7fffu + ((u >> 16) & 1u);   // RNE
  return (unsigned short)(r >> 16);
}

__device__ inline floatx4 mfma16(short4v a, short4v b, floatx4 c) {
#if __has_builtin(__builtin_amdgcn_mfma_f32_16x16x16bf16_1k)
  return __builtin_amdgcn_mfma_f32_16x16x16bf16_1k(a, b, c, 0, 0, 0);
#else
  asm("v_mfma_f32_16x16x16_bf16 %0, %1, %2, %0" : "+v"(c) : "v"(a), "v"(b));
  return c;
#endif
}

__device__ inline short4v u2s4(unsigned a, unsigned b) {
  union { unsigned u[2]; short4v s; } v;
  v.u[0] = a; v.u[1] = b;
  return v.s;
}

// -------- prologue: K -> bf16 rows; V -> bf16 transposed [bh][d][s] (straight) ------
__global__ __launch_bounds__(256) void conv_kv(const float* __restrict__ K,
                                               const float* __restrict__ V,
                                               unsigned short* __restrict__ Kb,
                                               unsigned short* __restrict__ Vb) {
  __shared__ __align__(16) unsigned short t[64 * 80];
  const int bh = blockIdx.y, s0 = blockIdx.x * 64;
  const int row = threadIdx.x >> 2, cp = threadIdx.x & 3;

  { // K: straight convert, coalesced
    const float* src = K + ((size_t)(bh * S_ + s0 + row)) * DK_ + cp * 16;
    unsigned short* dst = Kb + ((size_t)(bh * S_ + s0 + row)) * DK_ + cp * 16;
    #pragma unroll
    for (int h = 0; h < 2; ++h) {
      float4 a = *(const float4*)(src + h * 8);
      float4 b = *(const float4*)(src + h * 8 + 4);
      uint4 st;
      st.x = (unsigned)f2bf(a.x) | ((unsigned)f2bf(a.y) << 16);
      st.y = (unsigned)f2bf(a.z) | ((unsigned)f2bf(a.w) << 16);
      st.z = (unsigned)f2bf(b.x) | ((unsigned)f2bf(b.y) << 16);
      st.w = (unsigned)f2bf(b.z) | ((unsigned)f2bf(b.w) << 16);
      *(uint4*)(dst + h * 8) = st;
    }
  }
  { // V: transpose via LDS, straight store
    const float* src = V + ((size_t)(bh * S_ + s0 + row)) * DK_ + cp * 16;
    #pragma unroll
    for (int j4 = 0; j4 < 4; ++j4) {
      float4 a = *(const float4*)(src + j4 * 4);
      int c = cp * 16 + j4 * 4;
      t[(c + 0) * 80 + row] = f2bf(a.x);
      t[(c + 1) * 80 + row] = f2bf(a.y);
      t[(c + 2) * 80 + row] = f2bf(a.z);
      t[(c + 3) * 80 + row] = f2bf(a.w);
    }
    __syncthreads();
    unsigned short* dst = Vb + ((size_t)(bh * DK_ + row)) * S_ + s0 + cp * 16;
    *(uint4*)(dst + 0) = *(const uint4*)&t[row * 80 + cp * 16];
    *(uint4*)(dst + 8) = *(const uint4*)&t[row * 80 + cp * 16 + 8];
  }
}

// -------- flash attention: LDS-staged tiles + s-split compute -----------------------
// Staging: ring-3 LDS (48 KB), global_load_lds, counted vmcnt(4), 1 barrier/iter.
// Compute: wave w owns s-slice [w*16, w*16+16) x ALL 64 q. Per iter it reads only
// its disjoint 2 KB K-slice (2 ds_read_b128) + 2 KB V-slice (4 ds_read_b64), reused
// across all 4 q-subtiles -> 1x LDS amplification (vs 4x for the q-split form).
// Per-wave O^T partial spans 64q x 64d; cross-wave reduction once per block at the
// end through the (re-used) ring LDS.
__global__ __launch_bounds__(256, 3)
void fa_kernel(const float* __restrict__ Q, const unsigned short* __restrict__ Kb,
               const unsigned short* __restrict__ Vb, float* __restrict__ Out) {
  // ring slots: Kt[b] = SMEM + b*4096 shorts, Vt[b] = SMEM + (3+b)*4096 shorts
  // 64 rows x 8 chunks(16B) per tile, chunk c stored at p = c ^ (row&7)
  __shared__ __align__(16) unsigned short SMEM[6 * 4096];   // 48 KB

  const int tid  = threadIdx.x;
  const int wave = tid >> 6;        // s-slice within the 64-s kv tile
  const int lane = tid & 63;
  const int quad = lane >> 4;
  const int l16  = lane & 15;

  // XCD-aware decode + LPT (heaviest q-tiles first)
  const int id = blockIdx.x;
  const int bh = (id & 7) | (((id >> 3) & 3) << 3);
  const int qt = NQT - 1 - (id >> 5);   // 31..0
  const int nkv = qt + 1;

  const float SCL = 0.125f * 1.44269504088896340736f;  // 1/sqrt(64)*log2(e), folded into Q

  // ---- Q fragments, B-operand of S^T=K*Q^T: [nq*2+ks], lane n=q=l16, k=d=quad*8+j
  short8 qf[8];
  #pragma unroll
  for (int nq = 0; nq < 4; ++nq) {
    const float* p = Q + ((size_t)bh * S_ + qt * 64 + nq * 16 + l16) * DK_ + quad * 8;
    #pragma unroll
    for (int ks = 0; ks < 2; ++ks) {
      float4 x = *(const float4*)(p + ks * 32);
      float4 y = *(const float4*)(p + ks * 32 + 4);
      short8 t;
      t[0]=(short)f2bf(x.x*SCL); t[1]=(short)f2bf(x.y*SCL); t[2]=(short)f2bf(x.z*SCL); t[3]=(short)f2bf(x.w*SCL);
      t[4]=(short)f2bf(y.x*SCL); t[5]=(short)f2bf(y.y*SCL); t[6]=(short)f2bf(y.z*SCL); t[7]=(short)f2bf(y.w*SCL);
      qf[nq * 2 + ks] = t;
    }
  }

  floatx4 Ot[4][4];                 // O^T partials [dblk][nq] over this wave's s-slice
  float ls[4] = {0.f, 0.f, 0.f, 0.f};
  #pragma unroll
  for (int d = 0; d < 4; ++d)
    #pragma unroll
    for (int nq = 0; nq < 4; ++nq) Ot[d][nq] = (floatx4){0,0,0,0};

  auto stage = [&](int buf, int kv) {    // 4 global_load_lds (1 KiB each) per wave
    unsigned short* Ktb = SMEM + buf * 4096;
    unsigned short* Vtb = SMEM + (3 + buf) * 4096;
    #pragma unroll
    for (int rd = 0; rd < 2; ++rd) {
      const int cid = rd * 256 + wave * 64 + lane;
      const int row = cid >> 3;                 // K: s-row / V: d-row
      const int c   = (cid & 7) ^ (row & 7);    // store swizzle (chunk XOR by row)
      { // K tile
        const unsigned short* g = Kb + (((size_t)bh * S_ + kv * 64 + row) << 6) + (c << 3);
        __builtin_amdgcn_global_load_lds(
            (const __attribute__((address_space(1))) void*)g,
            (__attribute__((address_space(3))) void*)&Ktb[(rd * 4 + wave) * 512], 16, 0, 0);
      }
      { // V tile
        const unsigned short* g = Vb + (((size_t)(bh * DK_ + row)) << 11) + kv * 64 + (c << 3);
        __builtin_amdgcn_global_load_lds(
            (const __attribute__((address_space(1))) void*)g,
            (__attribute__((address_space(3))) void*)&Vtb[(rd * 4 + wave) * 512], 16, 0, 0);
      }
    }
  };

  auto computeT = [&](int cur, bool last) {
    const unsigned short* Ktc = SMEM + cur * 4096;
    const unsigned short* Vtc = SMEM + (3 + cur) * 4096;
    // K A-frag: row = wave*16+l16, d-chunk = ks*4+quad, swizzled by row&7 (= l16&7)
    const int rk = wave * 16 + l16;
    const short8 ck0 = *(const short8*)&Ktc[rk * 64 + ((quad    ) ^ (l16 & 7)) * 8];
    const short8 ck1 = *(const short8*)&Ktc[rk * 64 + ((quad + 4) ^ (l16 & 7)) * 8];
    // V^T A-frags: d-row = dblk*16+l16, s-offset = wave*16+quad*4
    //   chunk = wave*2 + (quad>>1), half = quad&1, swizzled by row&7 (= l16&7)
    short4v cv[4];
    #pragma unroll
    for (int dblk = 0; dblk < 4; ++dblk)
      cv[dblk] = *(const short4v*)&Vtc[(dblk * 16 + l16) * 64 +
                    ((wave * 2 + (quad >> 1)) ^ (l16 & 7)) * 8 + (quad & 1) * 4];
    // ---- QK^T + softmax-exp for the wave's 16-s x 64-q strip
    unsigned pk[4][2];
    #pragma unroll
    for (int nq = 0; nq < 4; ++nq) {
      if (last && nq < wave) continue;      // q-tile fully above diagonal (wave-uniform)
      floatx4 s0 = (floatx4){0,0,0,0};
      __builtin_amdgcn_s_setprio(1);
      s0 = __builtin_amdgcn_mfma_f32_16x16x32_bf16(ck0, qf[nq * 2 + 0], s0, 0, 0, 0);
      s0 = __builtin_amdgcn_mfma_f32_16x16x32_bf16(ck1, qf[nq * 2 + 1], s0, 0, 0, 0);
      __builtin_amdgcn_s_setprio(0);
      if (last && nq == wave) {   // diagonal 16x16: lane holds q=l16, s=quad*4+r
        #pragma unroll
        for (int r = 0; r < 4; ++r)
          if (quad * 4 + r > l16) s0[r] = -INFINITY;
      }
      float e0 = __builtin_amdgcn_exp2f(s0[0]);
      float e1 = __builtin_amdgcn_exp2f(s0[1]);
      float e2 = __builtin_amdgcn_exp2f(s0[2]);
      float e3 = __builtin_amdgcn_exp2f(s0[3]);
      ls[nq] += (e0 + e1) + (e2 + e3);
      pk[nq][0] = __builtin_amdgcn_perm(__float_as_uint(e1) + 0x8000u,
                                        __float_as_uint(e0) + 0x8000u, 0x07060302u);
      pk[nq][1] = __builtin_amdgcn_perm(__float_as_uint(e3) + 0x8000u,
                                        __float_as_uint(e2) + 0x8000u, 0x07060302u);
    }
    // ---- O^T += V^T * P^T : 16 independent accumulator chains
    __builtin_amdgcn_s_setprio(1);
    #pragma unroll
    for (int nq = 0; nq < 4; ++nq) {
      if (last && nq < wave) continue;
      const short4v pb = u2s4(pk[nq][0], pk[nq][1]);
      Ot[0][nq] = mfma16(cv[0], pb, Ot[0][nq]);
      Ot[1][nq] = mfma16(cv[1], pb, Ot[1][nq]);
      Ot[2][nq] = mfma16(cv[2], pb, Ot[2][nq]);
      Ot[3][nq] = mfma16(cv[3], pb, Ot[3][nq]);
    }
    __builtin_amdgcn_s_setprio(0);
  };

  // ---- main loop: ring-3, prefetch distance 2, ONE raw barrier per iteration.
  // At iter kv the wave has stage(kv) + stage(kv+1) outstanding (8 loads):
  // vmcnt(4) completes stage(kv) while stage(kv+1) stays in flight across the
  // barrier; stage(kv+2) issues after. Tail drains with vmcnt(0).
  stage(0, 0);
  if (nkv > 1) stage(1, 1);
  int cur = 0;
  for (int kv = 0; kv < nkv; ++kv) {
    if (kv + 1 < nkv) asm volatile("s_waitcnt vmcnt(4)" ::: "memory");
    else              asm volatile("s_waitcnt vmcnt(0)" ::: "memory");
    __builtin_amdgcn_s_barrier();
    if (kv + 2 < nkv) stage(cur == 0 ? 2 : cur - 1, kv + 2);   // slot (kv+2)%3
    computeT(cur, kv == nkv - 1);
    cur = (cur == 2) ? 0 : cur + 1;
  }

  // ---- epilogue: cross-wave reduction through re-used ring LDS (32 KB + 1 KB)
  floatx4* OredV = (floatx4*)SMEM;                 // [wave][db2][nq][lane] = 32 KB
  float*   Lred  = (float*)SMEM + 8192;           // [wave][nq][l16] at byte 32768
  #pragma unroll
  for (int nq = 0; nq < 4; ++nq) {
    ls[nq] += __shfl_xor(ls[nq], 16);
    ls[nq] += __shfl_xor(ls[nq], 32);
  }
  __syncthreads();   // ring buffers done being read by all waves
  if (lane < 16) {
    #pragma unroll
    for (int nq = 0; nq < 4; ++nq) Lred[(wave * 4 + nq) * 16 + lane] = ls[nq];
  }
  float inv = 0.f;
  #pragma unroll
  for (int rnd = 0; rnd < 2; ++rnd) {
    #pragma unroll
    for (int db = 0; db < 2; ++db)
      #pragma unroll
      for (int nq = 0; nq < 4; ++nq)
        OredV[((wave * 2 + db) * 4 + nq) * 64 + lane] = Ot[rnd * 2 + db][nq];
    __syncthreads();
    if (rnd == 0) {
      const float lt = Lred[(0 * 4 + wave) * 16 + l16] + Lred[(1 * 4 + wave) * 16 + l16]
                     + Lred[(2 * 4 + wave) * 16 + l16] + Lred[(3 * 4 + wave) * 16 + l16];
      inv = 1.0f / lt;
    }
    // wave w owns output q-rows [qt*64 + w*16, +16): sum its nq=w tiles over waves
    #pragma unroll
    for (int db = 0; db < 2; ++db) {
      floatx4 s = OredV[((0 * 2 + db) * 4 + wave) * 64 + lane]
                + OredV[((1 * 2 + db) * 4 + wave) * 64 + lane]
                + OredV[((2 * 2 + db) * 4 + wave) * 64 + lane]
                + OredV[((3 * 2 + db) * 4 + wave) * 64 + lane];
      s *= inv;
      // lane holds q = wave*16 + l16 (col), d = (rnd*2+db)*16 + quad*4 + r (row)
      *(floatx4*)(Out + ((size_t)(bh * S_ + qt * 64 + wave * 16 + l16)) * 64
                      + (rnd * 2 + db) * 16 + quad * 4) = s;
    }
    if (rnd == 0) __syncthreads();   // WAR before round-1 overwrites OredV
  }
}

extern "C" void kernel_launch(void* const* d_in, const int* in_sizes, int n_in,
                              void* d_out, int out_size, void* d_ws, size_t ws_size,
                              hipStream_t stream) {
  const float* Q = (const float*)d_in[0];
  const float* K = (const float*)d_in[1];
  const float* V = (const float*)d_in[2];
  // d_in[3] = d_k (=64), d_in[4] = causal tril mask (applied analytically)
  float* Out = (float*)d_out;
  unsigned short* Kb = (unsigned short*)d_ws;                    // 8.4 MB
  unsigned short* Vb = Kb + (size_t)BH_ * S_ * DK_;              // 8.4 MB
  conv_kv<<<dim3(S_ / 64, BH_), 256, 0, stream>>>(K, V, Kb, Vb);
  fa_kernel<<<dim3(NQT * BH_), 256, 0, stream>>>(Q, Kb, Vb, Out);
}

// Round 5
// 142.075 us; speedup vs baseline: 1.1492x; 1.0168x over previous
//
#include <hip/hip_runtime.h>
#include <cstdint>

#define B_ 2
#define H_ 16
#define S_ 2048
#define DK_ 64
#define BH_ (B_*H_)
#define NQT 32    // 64-row q tiles

typedef __attribute__((ext_vector_type(8))) short short8;
typedef __attribute__((ext_vector_type(4))) short short4v;
typedef __attribute__((ext_vector_type(4))) float floatx4;

__device__ inline unsigned short f2bf(float f) {
  union { float f; unsigned u; } v; v.f = f;
  unsigned u = v.u;
  unsigned r = u + 0x7fffu + ((u >> 16) & 1u);   // RNE
  return (unsigned short)(r >> 16);
}

__device__ inline floatx4 mfma16(short4v a, short4v b, floatx4 c) {
#if __has_builtin(__builtin_amdgcn_mfma_f32_16x16x16bf16_1k)
  return __builtin_amdgcn_mfma_f32_16x16x16bf16_1k(a, b, c, 0, 0, 0);
#else
  asm("v_mfma_f32_16x16x16_bf16 %0, %1, %2, %0" : "+v"(c) : "v"(a), "v"(b));
  return c;
#endif
}

__device__ inline short4v u2s4(unsigned a, unsigned b) {
  union { unsigned u[2]; short4v s; } v;
  v.u[0] = a; v.u[1] = b;
  return v.s;
}

// -------- prologue: K -> bf16 rows; V -> bf16 transposed [bh][d][s] (straight) ------
__global__ __launch_bounds__(256) void conv_kv(const float* __restrict__ K,
                                               const float* __restrict__ V,
                                               unsigned short* __restrict__ Kb,
                                               unsigned short* __restrict__ Vb) {
  __shared__ __align__(16) unsigned short t[64 * 80];
  const int bh = blockIdx.y, s0 = blockIdx.x * 64;
  const int row = threadIdx.x >> 2, cp = threadIdx.x & 3;

  { // K: straight convert, coalesced
    const float* src = K + ((size_t)(bh * S_ + s0 + row)) * DK_ + cp * 16;
    unsigned short* dst = Kb + ((size_t)(bh * S_ + s0 + row)) * DK_ + cp * 16;
    #pragma unroll
    for (int h = 0; h < 2; ++h) {
      float4 a = *(const float4*)(src + h * 8);
      float4 b = *(const float4*)(src + h * 8 + 4);
      uint4 st;
      st.x = (unsigned)f2bf(a.x) | ((unsigned)f2bf(a.y) << 16);
      st.y = (unsigned)f2bf(a.z) | ((unsigned)f2bf(a.w) << 16);
      st.z = (unsigned)f2bf(b.x) | ((unsigned)f2bf(b.y) << 16);
      st.w = (unsigned)f2bf(b.z) | ((unsigned)f2bf(b.w) << 16);
      *(uint4*)(dst + h * 8) = st;
    }
  }
  { // V: transpose via LDS, straight store
    const float* src = V + ((size_t)(bh * S_ + s0 + row)) * DK_ + cp * 16;
    #pragma unroll
    for (int j4 = 0; j4 < 4; ++j4) {
      float4 a = *(const float4*)(src + j4 * 4);
      int c = cp * 16 + j4 * 4;
      t[(c + 0) * 80 + row] = f2bf(a.x);
      t[(c + 1) * 80 + row] = f2bf(a.y);
      t[(c + 2) * 80 + row] = f2bf(a.z);
      t[(c + 3) * 80 + row] = f2bf(a.w);
    }
    __syncthreads();
    unsigned short* dst = Vb + ((size_t)(bh * DK_ + row)) * S_ + s0 + cp * 16;
    *(uint4*)(dst + 0) = *(const uint4*)&t[row * 80 + cp * 16];
    *(uint4*)(dst + 8) = *(const uint4*)&t[row * 80 + cp * 16 + 8];
  }
}

// -------- flash attention: barrier-free per-wave pipelines --------------------------
// Wave w owns s-slice [16w,16w+16) x all 64q, and stages its OWN private ring-2 LDS
// arena (K-slice 2 KB [16 rows x 64d, chunk-swizzled] + V-slice 2 KB [64d x 16s,
// h-chunk swizzled] per slot). vmcnt is per-wave, slices are wave-private ->
// NO barriers in the main loop: 12 independent wave-pipelines per CU, each with
// issue-early staging (stage(kv+1) issued before waiting on stage(kv)).
__global__ __launch_bounds__(256, 3)
void fa_kernel(const float* __restrict__ Q, const unsigned short* __restrict__ Kb,
               const unsigned short* __restrict__ Vb, float* __restrict__ Out) {
  // per-wave arena: wave*4096 shorts; slot s at +s*2048 (K at +0, V at +1024 shorts)
  // + 512 shorts for the epilogue l-reduction = 33 KB total
  __shared__ __align__(16) unsigned short SMEM[4 * 4096 + 512];

  const int tid  = threadIdx.x;
  const int wave = tid >> 6;        // s-slice within the 64-s kv tile
  const int lane = tid & 63;
  const int quad = lane >> 4;
  const int l16  = lane & 15;

  // XCD-aware decode + LPT (heaviest q-tiles first)
  const int id = blockIdx.x;
  const int bh = (id & 7) | (((id >> 3) & 3) << 3);
  const int qt = NQT - 1 - (id >> 5);   // 31..0
  const int nkv = qt + 1;

  const float SCL = 0.125f * 1.44269504088896340736f;  // 1/sqrt(64)*log2(e), folded into Q

  // ---- Q fragments, B-operand of S^T=K*Q^T: [nq*2+ks], lane n=q=l16, k=d=quad*8+j
  short8 qf[8];
  #pragma unroll
  for (int nq = 0; nq < 4; ++nq) {
    const float* p = Q + ((size_t)bh * S_ + qt * 64 + nq * 16 + l16) * DK_ + quad * 8;
    #pragma unroll
    for (int ks = 0; ks < 2; ++ks) {
      float4 x = *(const float4*)(p + ks * 32);
      float4 y = *(const float4*)(p + ks * 32 + 4);
      short8 t;
      t[0]=(short)f2bf(x.x*SCL); t[1]=(short)f2bf(x.y*SCL); t[2]=(short)f2bf(x.z*SCL); t[3]=(short)f2bf(x.w*SCL);
      t[4]=(short)f2bf(y.x*SCL); t[5]=(short)f2bf(y.y*SCL); t[6]=(short)f2bf(y.z*SCL); t[7]=(short)f2bf(y.w*SCL);
      qf[nq * 2 + ks] = t;
    }
  }

  floatx4 Ot[4][4];                 // O^T partials [dblk][nq] over this wave's s-slice
  float ls[4] = {0.f, 0.f, 0.f, 0.f};
  #pragma unroll
  for (int d = 0; d < 4; ++d)
    #pragma unroll
    for (int nq = 0; nq < 4; ++nq) Ot[d][nq] = (floatx4){0,0,0,0};

  // stage the wave's PRIVATE slices for kv-tile kv into its slot (4 global_load_lds)
  auto stage = [&](int slot, int kv) {
    unsigned short* base = SMEM + wave * 4096 + slot * 2048;
    #pragma unroll
    for (int j = 0; j < 2; ++j) {
      const int kap = 64 * j + lane;      // chunk id within the slice
      { // K slice: 16 rows x 64 d; row r (128 B), chunk c stored at slot c^(r&7)
        const int r = kap >> 3;
        const int c = (kap & 7) ^ (r & 7);
        const unsigned short* g =
            Kb + (((size_t)(bh * S_ + kv * 64 + wave * 16 + r)) << 6) + (c << 3);
        __builtin_amdgcn_global_load_lds(
            (const __attribute__((address_space(1))) void*)g,
            (__attribute__((address_space(3))) void*)(base + j * 512), 16, 0, 0);
      }
      { // V slice: 64 d-rows x 16 s; row d (32 B) as 2 h-chunks, stored at h^(d&1)
        const int d = kap >> 1;
        const int h = (kap & 1) ^ ((kap >> 1) & 1);
        const unsigned short* g =
            Vb + (((size_t)(bh * DK_ + d)) << 11) + kv * 64 + wave * 16 + h * 8;
        __builtin_amdgcn_global_load_lds(
            (const __attribute__((address_space(1))) void*)g,
            (__attribute__((address_space(3))) void*)(base + 1024 + j * 512), 16, 0, 0);
      }
    }
  };

  auto computeT = [&](int slot, bool last) {
    const unsigned short* kb_ = SMEM + wave * 4096 + slot * 2048;
    const unsigned short* vb_ = kb_ + 1024;
    // K A-frag: local row = l16, d-chunk = ks*4+quad, stored swizzled by row&7
    const short8 ck0 = *(const short8*)&kb_[l16 * 64 + ((quad    ) ^ (l16 & 7)) * 8];
    const short8 ck1 = *(const short8*)&kb_[l16 * 64 + ((quad + 4) ^ (l16 & 7)) * 8];
    // V^T A-frags: d-row = dblk*16+l16 (32 B rows), s-local = quad*4, h-chunk swizzled
    short4v cv[4];
    #pragma unroll
    for (int dblk = 0; dblk < 4; ++dblk)
      cv[dblk] = *(const short4v*)&vb_[(dblk * 16 + l16) * 16 +
                    (((quad >> 1) ^ (l16 & 1)) * 8) + (quad & 1) * 4];
    // ---- QK^T + softmax-exp for the wave's 16-s x 64-q strip
    unsigned pk[4][2];
    #pragma unroll
    for (int nq = 0; nq < 4; ++nq) {
      if (last && nq < wave) continue;      // q-tile fully above diagonal (wave-uniform)
      floatx4 s0 = (floatx4){0,0,0,0};
      __builtin_amdgcn_s_setprio(1);
      s0 = __builtin_amdgcn_mfma_f32_16x16x32_bf16(ck0, qf[nq * 2 + 0], s0, 0, 0, 0);
      s0 = __builtin_amdgcn_mfma_f32_16x16x32_bf16(ck1, qf[nq * 2 + 1], s0, 0, 0, 0);
      __builtin_amdgcn_s_setprio(0);
      if (last && nq == wave) {   // diagonal 16x16: lane holds q=l16, s=quad*4+r
        #pragma unroll
        for (int r = 0; r < 4; ++r)
          if (quad * 4 + r > l16) s0[r] = -INFINITY;
      }
      float e0 = __builtin_amdgcn_exp2f(s0[0]);
      float e1 = __builtin_amdgcn_exp2f(s0[1]);
      float e2 = __builtin_amdgcn_exp2f(s0[2]);
      float e3 = __builtin_amdgcn_exp2f(s0[3]);
      ls[nq] += (e0 + e1) + (e2 + e3);
      pk[nq][0] = __builtin_amdgcn_perm(__float_as_uint(e1) + 0x8000u,
                                        __float_as_uint(e0) + 0x8000u, 0x07060302u);
      pk[nq][1] = __builtin_amdgcn_perm(__float_as_uint(e3) + 0x8000u,
                                        __float_as_uint(e2) + 0x8000u, 0x07060302u);
    }
    // ---- O^T += V^T * P^T : 16 independent accumulator chains
    __builtin_amdgcn_s_setprio(1);
    #pragma unroll
    for (int nq = 0; nq < 4; ++nq) {
      if (last && nq < wave) continue;
      const short4v pb = u2s4(pk[nq][0], pk[nq][1]);
      Ot[0][nq] = mfma16(cv[0], pb, Ot[0][nq]);
      Ot[1][nq] = mfma16(cv[1], pb, Ot[1][nq]);
      Ot[2][nq] = mfma16(cv[2], pb, Ot[2][nq]);
      Ot[3][nq] = mfma16(cv[3], pb, Ot[3][nq]);
    }
    __builtin_amdgcn_s_setprio(0);
  };

  // ---- main loop: NO barriers. Private ring-2, issue-early staging:
  // at iter kv, issue stage(kv+1) first, then vmcnt(4) completes stage(kv)'s 4 loads
  // (in-order retire) while stage(kv+1)'s 4 stay in flight with a full compute-phase
  // of lead. WAR: stage(kv+1)'s slot was read by compute(kv-1), already complete in
  // this wave's program order (every ds_read has a dependent MFMA behind an lgkm wait).
  stage(0, 0);
  for (int kv = 0; kv < nkv; ++kv) {
    const int slot = kv & 1;
    if (kv + 1 < nkv) {
      stage(slot ^ 1, kv + 1);
      asm volatile("s_waitcnt vmcnt(4)" ::: "memory");
    } else {
      asm volatile("s_waitcnt vmcnt(0)" ::: "memory");
    }
    computeT(slot, kv == nkv - 1);
  }

  // ---- epilogue: cross-wave reduction through re-used LDS (32 KB + 1 KB)
  floatx4* OredV = (floatx4*)SMEM;                     // [wave][db2][nq][lane] = 32 KB
  float*   Lred  = (float*)(SMEM + 4 * 4096);          // [wave][nq][l16] (the +512 tail)
  #pragma unroll
  for (int nq = 0; nq < 4; ++nq) {
    ls[nq] += __shfl_xor(ls[nq], 16);
    ls[nq] += __shfl_xor(ls[nq], 32);
  }
  __syncthreads();   // all waves done with their private ring arenas
  if (lane < 16) {
    #pragma unroll
    for (int nq = 0; nq < 4; ++nq) Lred[(wave * 4 + nq) * 16 + lane] = ls[nq];
  }
  float inv = 0.f;
  #pragma unroll
  for (int rnd = 0; rnd < 2; ++rnd) {
    #pragma unroll
    for (int db = 0; db < 2; ++db)
      #pragma unroll
      for (int nq = 0; nq < 4; ++nq)
        OredV[((wave * 2 + db) * 4 + nq) * 64 + lane] = Ot[rnd * 2 + db][nq];
    __syncthreads();
    if (rnd == 0) {
      const float lt = Lred[(0 * 4 + wave) * 16 + l16] + Lred[(1 * 4 + wave) * 16 + l16]
                     + Lred[(2 * 4 + wave) * 16 + l16] + Lred[(3 * 4 + wave) * 16 + l16];
      inv = 1.0f / lt;
    }
    // wave w owns output q-rows [qt*64 + w*16, +16): sum its nq=w tiles over waves
    #pragma unroll
    for (int db = 0; db < 2; ++db) {
      floatx4 s = OredV[((0 * 2 + db) * 4 + wave) * 64 + lane]
                + OredV[((1 * 2 + db) * 4 + wave) * 64 + lane]
                + OredV[((2 * 2 + db) * 4 + wave) * 64 + lane]
                + OredV[((3 * 2 + db) * 4 + wave) * 64 + lane];
      s *= inv;
      // lane holds q = wave*16 + l16 (col), d = (rnd*2+db)*16 + quad*4 + r (row)
      *(floatx4*)(Out + ((size_t)(bh * S_ + qt * 64 + wave * 16 + l16)) * 64
                      + (rnd * 2 + db) * 16 + quad * 4) = s;
    }
    if (rnd == 0) __syncthreads();   // WAR before round-1 overwrites OredV
  }
}

extern "C" void kernel_launch(void* const* d_in, const int* in_sizes, int n_in,
                              void* d_out, int out_size, void* d_ws, size_t ws_size,
                              hipStream_t stream) {
  const float* Q = (const float*)d_in[0];
  const float* K = (const float*)d_in[1];
  const float* V = (const float*)d_in[2];
  // d_in[3] = d_k (=64), d_in[4] = causal tril mask (applied analytically)
  float* Out = (float*)d_out;
  unsigned short* Kb = (unsigned short*)d_ws;                    // 8.4 MB
  unsigned short* Vb = Kb + (size_t)BH_ * S_ * DK_;              // 8.4 MB
  conv_kv<<<dim3(S_ / 64, BH_), 256, 0, stream>>>(K, V, Kb, Vb);
  fa_kernel<<<dim3(NQT * BH_), 256, 0, stream>>>(Q, Kb, Vb, Out);
}

// Round 8
// 132.052 us; speedup vs baseline: 1.2364x; 1.0759x over previous
//
#include <hip/hip_runtime.h>
#include <cstdint>

#define B_ 2
#define H_ 16
#define S_ 2048
#define DK_ 64
#define BH_ (B_*H_)
#define NQT 32    // 64-row q tiles

typedef __attribute__((ext_vector_type(8))) short short8;
typedef __attribute__((ext_vector_type(4))) float floatx4;
typedef __attribute__((ext_vector_type(16))) float floatx16;

__device__ inline unsigned short f2bf(float f) {
  union { float f; unsigned u; } v; v.f = f;
  unsigned u = v.u;
  unsigned r = u + 0x7fffu + ((u >> 16) & 1u);   // RNE
  return (unsigned short)(r >> 16);
}

__device__ inline floatx16 mfma32(short8 a, short8 b, floatx16 c) {
  return __builtin_amdgcn_mfma_f32_32x32x16_bf16(a, b, c, 0, 0, 0);
}

// -------- prologue: K -> bf16 rows; V -> bf16 transposed [bh][d][s] (straight) ------
__global__ __launch_bounds__(256) void conv_kv(const float* __restrict__ K,
                                               const float* __restrict__ V,
                                               unsigned short* __restrict__ Kb,
                                               unsigned short* __restrict__ Vb) {
  __shared__ __align__(16) unsigned short t[64 * 80];
  const int bh = blockIdx.y, s0 = blockIdx.x * 64;
  const int row = threadIdx.x >> 2, cp = threadIdx.x & 3;

  { // K: straight convert, coalesced
    const float* src = K + ((size_t)(bh * S_ + s0 + row)) * DK_ + cp * 16;
    unsigned short* dst = Kb + ((size_t)(bh * S_ + s0 + row)) * DK_ + cp * 16;
    #pragma unroll
    for (int h = 0; h < 2; ++h) {
      float4 a = *(const float4*)(src + h * 8);
      float4 b = *(const float4*)(src + h * 8 + 4);
      uint4 st;
      st.x = (unsigned)f2bf(a.x) | ((unsigned)f2bf(a.y) << 16);
      st.y = (unsigned)f2bf(a.z) | ((unsigned)f2bf(a.w) << 16);
      st.z = (unsigned)f2bf(b.x) | ((unsigned)f2bf(b.y) << 16);
      st.w = (unsigned)f2bf(b.z) | ((unsigned)f2bf(b.w) << 16);
      *(uint4*)(dst + h * 8) = st;
    }
  }
  { // V: transpose via LDS, straight store
    const float* src = V + ((size_t)(bh * S_ + s0 + row)) * DK_ + cp * 16;
    #pragma unroll
    for (int j4 = 0; j4 < 4; ++j4) {
      float4 a = *(const float4*)(src + j4 * 4);
      int c = cp * 16 + j4 * 4;
      t[(c + 0) * 80 + row] = f2bf(a.x);
      t[(c + 1) * 80 + row] = f2bf(a.y);
      t[(c + 2) * 80 + row] = f2bf(a.z);
      t[(c + 3) * 80 + row] = f2bf(a.w);
    }
    __syncthreads();
    unsigned short* dst = Vb + ((size_t)(bh * DK_ + row)) * S_ + s0 + cp * 16;
    *(uint4*)(dst + 0) = *(const uint4*)&t[row * 80 + cp * 16];
    *(uint4*)(dst + 8) = *(const uint4*)&t[row * 80 + cp * 16 + 8];
  }
}

// -------- flash attention: 32x32 MFMA, swapped QK^T, permlane P-realign -------------
// Block = 64q x 64s tiles, 4 waves as (wq,ws) quadrants (32q x 32s each).
// S^T = K*Q^T via 4x mfma_32x32x16 (d-loop); C-layout: col q=l&31,
// row s=(reg&3)+8(reg>>2)+4(l>>5). exp2 in-register, pack to bf16 with
// v_cvt_pk_bf16_f32, realign s-groups across lane-halves with v_permlane32_swap_b32
// (semantics: swap(a,b) -> a'={a.lo,b.lo}, b'={a.hi,b.hi}; LOW s-group must be the
// FIRST operand) so P^T feeds PV's B-operand (k=(l>>5)*8+j) directly.
// O^T += V^T*P^T via 4x mfma_32x32x16. Ring-2 LDS staging (global_load_lds, XOR
// swizzle), one vmcnt(0)+barrier per iter. All 1024 blocks co-resident (4/CU);
// qt decoded so every CU-residue class {u,u+8,u+16,u+24} gets equal work (66 iters).
__global__ __launch_bounds__(256, 4)
void fa_kernel(const float* __restrict__ Q, const unsigned short* __restrict__ Kb,
               const unsigned short* __restrict__ Vb, float* __restrict__ Out) {
  // slot s at SMEM + s*8192: Kt = +0 (64 rows x 64d), Vt = +4096 (64 d-rows x 64s)
  // rows 128 B = 8 chunks of 16 B; chunk c stored at position c^(row&7)
  __shared__ __align__(16) unsigned short SMEM[2 * 8192 + 256];

  const int tid  = threadIdx.x;
  const int wave = tid >> 6;
  const int lane = tid & 63;
  const int l31  = lane & 31;
  const int h    = lane >> 5;
  const int wq   = wave >> 1;   // q-half of the 64-q tile
  const int ws   = wave & 1;    // s-half of the 64-s kv tile

  const int id = blockIdx.x;
  const int bh = id & 31;                 // low 5 bits: id%8 spreads bh over XCDs
  const int u  = id >> 5;                 // 0..31
  const int r  = u & 7, k4 = u >> 3;
  const int qt = (k4 == 0) ? r : (k4 == 1) ? (15 - r) : (k4 == 2) ? (16 + r) : (31 - r);
  const int nkv = qt + 1;

  const float SCL = 0.125f * 1.44269504088896340736f;  // 1/sqrt(64)*log2(e) into Q

  // ---- Q fragments, B-operand of S^T=K*Q^T (32x32x16): lane: q=l31, k=h*8+j
  short8 qf[4];
  {
    const float* qp = Q + ((size_t)bh * S_ + qt * 64 + wq * 32 + l31) * DK_ + h * 8;
    #pragma unroll
    for (int dstep = 0; dstep < 4; ++dstep) {
      float4 x = *(const float4*)(qp + dstep * 16);
      float4 y = *(const float4*)(qp + dstep * 16 + 4);
      short8 t;
      t[0]=(short)f2bf(x.x*SCL); t[1]=(short)f2bf(x.y*SCL); t[2]=(short)f2bf(x.z*SCL); t[3]=(short)f2bf(x.w*SCL);
      t[4]=(short)f2bf(y.x*SCL); t[5]=(short)f2bf(y.y*SCL); t[6]=(short)f2bf(y.z*SCL); t[7]=(short)f2bf(y.w*SCL);
      qf[dstep] = t;
    }
  }

  floatx16 Ot[2] = { {0,0,0,0,0,0,0,0,0,0,0,0,0,0,0,0},
                     {0,0,0,0,0,0,0,0,0,0,0,0,0,0,0,0} };  // O^T [dsub: 32d each]
  float ls = 0.f;

  auto stage = [&](int slot, int kv) {   // 4 global_load_lds per thread (K:2, V:2)
    #pragma unroll
    for (int rd = 0; rd < 2; ++rd) {
      const int cid = rd * 256 + tid;
      const int row = cid >> 3;
      const int c   = (cid & 7) ^ (row & 7);
      { // K tile
        const unsigned short* g = Kb + (((size_t)bh * S_ + kv * 64 + row) << 6) + (c << 3);
        __builtin_amdgcn_global_load_lds(
            (const __attribute__((address_space(1))) void*)g,
            (__attribute__((address_space(3))) void*)&SMEM[slot * 8192 + rd * 2048 + wave * 512],
            16, 0, 0);
      }
      { // V tile
        const unsigned short* g = Vb + (((size_t)(bh * DK_ + row)) << 11) + kv * 64 + (c << 3);
        __builtin_amdgcn_global_load_lds(
            (const __attribute__((address_space(1))) void*)g,
            (__attribute__((address_space(3))) void*)&SMEM[slot * 8192 + 4096 + rd * 2048 + wave * 512],
            16, 0, 0);
      }
    }
  };

  auto computeT = [&](int cur, bool diag) {
    if (diag && wq == 0 && ws == 1) return;   // quadrant fully above diagonal
    const unsigned short* Kt = SMEM + cur * 8192;
    const unsigned short* Vt = Kt + 4096;
    // ---- S^T = K * Q^T over this wave's 32s x 32q quadrant
    floatx16 s = {0,0,0,0,0,0,0,0,0,0,0,0,0,0,0,0};
    const int krow = ws * 32 + l31;
    #pragma unroll
    for (int dstep = 0; dstep < 4; ++dstep) {
      const short8 a = *(const short8*)&Kt[krow * 64 + (((dstep << 1) + h) ^ (krow & 7)) * 8];
      s = mfma32(a, qf[dstep], s);
    }
    if (diag && wq == ws) {   // elementwise causal mask on the diagonal quadrant
      #pragma unroll
      for (int rg = 0; rg < 16; ++rg) {
        const int sl = (rg & 3) + 8 * (rg >> 2) + 4 * h;
        if (sl > l31) s[rg] = -INFINITY;
      }
    }
    // ---- exp2 + row-sum (lane's 16 values all share q=l31)
    float e[16];
    #pragma unroll
    for (int i = 0; i < 16; ++i) e[i] = __builtin_amdgcn_exp2f(s[i]);
    ls += (((e[0]+e[1])+(e[2]+e[3])) + ((e[4]+e[5])+(e[6]+e[7])))
        + (((e[8]+e[9])+(e[10]+e[11])) + ((e[12]+e[13])+(e[14]+e[15])));
    // ---- pack P^T to bf16 B-operands: per 16-s k-step, cvt_pk pairs then
    // permlane32_swap. swap(a,b): a'={a.lo,b.lo}, b'={a.hi,b.hi}. With
    // X=pk(low s-group regs), Y=pk(high s-group regs), swap(X,Y) gives
    // X' = word{j01}: {own s-grp0 | partner s-grp2}, Y' = word{j45}:
    // {partner s-grp1 | own s-grp3} -- exactly B's k=(l>>5)*8+j layout.
    short8 pb[2];
    #pragma unroll
    for (int t = 0; t < 2; ++t) {
      unsigned X0, X1, Y0, Y1;
      asm("v_cvt_pk_bf16_f32 %0, %1, %2" : "=v"(X0) : "v"(e[8*t+0]), "v"(e[8*t+1]));
      asm("v_cvt_pk_bf16_f32 %0, %1, %2" : "=v"(X1) : "v"(e[8*t+2]), "v"(e[8*t+3]));
      asm("v_cvt_pk_bf16_f32 %0, %1, %2" : "=v"(Y0) : "v"(e[8*t+4]), "v"(e[8*t+5]));
      asm("v_cvt_pk_bf16_f32 %0, %1, %2" : "=v"(Y1) : "v"(e[8*t+6]), "v"(e[8*t+7]));
      asm("v_permlane32_swap_b32 %0, %1" : "+v"(X0), "+v"(Y0));
      asm("v_permlane32_swap_b32 %0, %1" : "+v"(X1), "+v"(Y1));
      union { unsigned u[4]; short8 s8; } pbu;
      pbu.u[0] = X0; pbu.u[1] = X1; pbu.u[2] = Y0; pbu.u[3] = Y1;
      pb[t] = pbu.s8;
    }
    // ---- O^T += V^T * P^T over this wave's s-half (2 d-subtiles x 2 k-steps)
    #pragma unroll
    for (int dsub = 0; dsub < 2; ++dsub) {
      const int vrow = dsub * 32 + l31;
      const short8 v0 = *(const short8*)&Vt[vrow * 64 + (((ws << 2) + h    ) ^ (vrow & 7)) * 8];
      const short8 v1 = *(const short8*)&Vt[vrow * 64 + (((ws << 2) + h + 2) ^ (vrow & 7)) * 8];
      Ot[dsub] = mfma32(v0, pb[0], Ot[dsub]);
      Ot[dsub] = mfma32(v1, pb[1], Ot[dsub]);
    }
  };

  // ---- main loop: ring-2, stage(kv+1) issued right after the barrier ->
  // one full compute phase of lead; vmcnt(0)+barrier makes the tile visible
  // block-wide. WAR: stage(kv+1) overwrites the slot read by compute(kv-1),
  // complete for all waves once they pass this iteration's barrier (every
  // ds_read has a dependent MFMA behind a compiler lgkmcnt wait).
  stage(0, 0);
  for (int kv = 0; kv < nkv; ++kv) {
    asm volatile("s_waitcnt vmcnt(0)" ::: "memory");
    __builtin_amdgcn_s_barrier();
    if (kv + 1 < nkv) stage((kv + 1) & 1, kv + 1);
    computeT(kv & 1, kv == nkv - 1);
  }

  // ---- epilogue: ws=1 -> LDS, ws=0 adds, scales by 1/l, stores
  ls += __shfl_xor(ls, 32);            // combine lane-halves (complementary s-rows)
  float* OP = (float*)SMEM;            // [wq][dsub][reg][64] = 4096 floats (16 KB)
  float* LP = OP + 4096;               // [wq][64]
  __syncthreads();                     // everyone done reading ring slots
  if (ws == 1) {
    #pragma unroll
    for (int dsub = 0; dsub < 2; ++dsub)
      #pragma unroll
      for (int rg = 0; rg < 16; ++rg)
        OP[((wq * 2 + dsub) * 16 + rg) * 64 + lane] = Ot[dsub][rg];
    LP[wq * 64 + lane] = ls;
  }
  __syncthreads();
  if (ws == 0) {
    const float inv = 1.0f / (ls + LP[wq * 64 + lane]);
    float* og = Out + ((size_t)(bh * S_ + qt * 64 + wq * 32 + l31)) * DK_;
    #pragma unroll
    for (int dsub = 0; dsub < 2; ++dsub) {
      #pragma unroll
      for (int g = 0; g < 4; ++g) {
        floatx4 o;
        #pragma unroll
        for (int j = 0; j < 4; ++j)
          o[j] = (Ot[dsub][4 * g + j] + OP[((wq * 2 + dsub) * 16 + 4 * g + j) * 64 + lane]) * inv;
        // d = dsub*32 + 8g + 4h + {0..3}
        *(floatx4*)(og + dsub * 32 + 8 * g + 4 * h) = o;
      }
    }
  }
}

extern "C" void kernel_launch(void* const* d_in, const int* in_sizes, int n_in,
                              void* d_out, int out_size, void* d_ws, size_t ws_size,
                              hipStream_t stream) {
  const float* Q = (const float*)d_in[0];
  const float* K = (const float*)d_in[1];
  const float* V = (const float*)d_in[2];
  // d_in[3] = d_k (=64), d_in[4] = causal tril mask (applied analytically)
  float* Out = (float*)d_out;
  unsigned short* Kb = (unsigned short*)d_ws;                    // 8.4 MB
  unsigned short* Vb = Kb + (size_t)BH_ * S_ * DK_;              // 8.4 MB
  conv_kv<<<dim3(S_ / 64, BH_), 256, 0, stream>>>(K, V, Kb, Vb);
  fa_kernel<<<dim3(NQT * BH_), 256, 0, stream>>>(Q, Kb, Vb, Out);
}